// Round 2
// baseline (533.694 us; speedup 1.0000x reference)
//
#include <hip/hip_runtime.h>
#include <hip/hip_bf16.h>

// AngularMarginLoss: B=2048, D=256, C=100000
// loss = -mean_b( num_b - log(exp(num_b) + sum_{c!=t_b} exp(30*cos_bc) + 1e-6) )
// num_b = 30*cos(acos(clip(cos_bt)) + 0.2)
//
// Round-2 structure: barrier-free k_main. Each wave owns 64 classes (4 MFMA
// col-tiles, persistent normalized-bf16 A-fragments in 128 VGPRs) x 512
// samples (B split 4-way across the block's waves for occupancy). B-fragments
// load directly from global (embbf is 1MB -> L2-resident). Partial row-sums
// go out as plain coalesced stores; k_rowsum reduces, k_loss finishes.

static constexpr int Bn = 2048;
static constexpr int Dn = 256;
static constexpr int Cn = 100000;
static constexpr int COLS_PER_WAVE = 64;                                  // 4 tiles x 16
static constexpr int NCG = (Cn + COLS_PER_WAVE - 1) / COLS_PER_WAVE;      // 1563
static constexpr float OOB_COLS = (float)(NCG * COLS_PER_WAVE - Cn);      // 32
static constexpr int SAMPLES_PER_WAVE = 512;                              // B/4

#define SCALE_F 30.0f
#define MARGIN_F 0.2f
#define EPS_F 1e-6f

typedef __attribute__((ext_vector_type(8))) short bf16x8;   // 8 bf16 = 4 VGPRs
typedef __attribute__((ext_vector_type(4))) float f32x4;

__device__ __forceinline__ short f2bf_rne(float x) {
    union { float f; unsigned int u; } v; v.f = x;
    unsigned int r = v.u + 0x7fffu + ((v.u >> 16) & 1u);
    return (short)(r >> 16);
}

// ---- kernel 1: emb fp32 -> bf16 (row-major, 2048x256) ----
__global__ __launch_bounds__(256) void k_emb2bf(const float* __restrict__ emb,
                                                short* __restrict__ out) {
    int i = (blockIdx.x * 256 + threadIdx.x) * 4;   // 512 blocks covers 524288 exactly
    float4 x = *(const float4*)(emb + i);
    short4 o;
    o.x = f2bf_rne(x.x); o.y = f2bf_rne(x.y);
    o.z = f2bf_rne(x.z); o.w = f2bf_rne(x.w);
    *(short4*)(out + i) = o;
}

// ---- kernel 2: main fused GEMM + exp row-sum (barrier-free) ----
// Block = 4 waves, all with the same 64 columns (colgroup = blockIdx.x) but
// disjoint 512-sample ranges. No __syncthreads, no LDS, no atomics.
__global__ __launch_bounds__(256, 2) void k_main(const float* __restrict__ W,
                                                 const short* __restrict__ embbf,
                                                 float* __restrict__ partial) {
    const int tid  = threadIdx.x;
    const int wave = tid >> 6;
    const int lane = tid & 63;
    const int q    = lane >> 4;   // quad 0..3
    const int cr   = lane & 15;
    const int cg   = blockIdx.x;
    const int cbase = cg * COLS_PER_WAVE;
    const int sbase = wave * SAMPLES_PER_WAVE;

    // ---- prologue: normalized bf16 A-fragments for 4 col-tiles ----
    // A layout (16x16x32): lane holds A[m=lane&15][k = q*8 + j] per 32-wide k-step.
    // All 4 waves load the same 64 W rows (L1-shared); normalize fused here.
    bf16x8 afrag[4][8];
#pragma unroll
    for (int ct = 0; ct < 4; ++ct) {
        const int c = cbase + ct * 16 + cr;
        float wtmp[64];
        float ss = 0.0f;
        if (c < Cn) {
            const float* wr = W + (long)c * Dn;
#pragma unroll
            for (int ks = 0; ks < 8; ++ks) {
                float4 x0 = *(const float4*)(wr + ks * 32 + q * 8);
                float4 x1 = *(const float4*)(wr + ks * 32 + q * 8 + 4);
                wtmp[ks * 8 + 0] = x0.x; wtmp[ks * 8 + 1] = x0.y;
                wtmp[ks * 8 + 2] = x0.z; wtmp[ks * 8 + 3] = x0.w;
                wtmp[ks * 8 + 4] = x1.x; wtmp[ks * 8 + 5] = x1.y;
                wtmp[ks * 8 + 6] = x1.z; wtmp[ks * 8 + 7] = x1.w;
                ss += x0.x * x0.x + x0.y * x0.y + x0.z * x0.z + x0.w * x0.w;
                ss += x1.x * x1.x + x1.y * x1.y + x1.z * x1.z + x1.w * x1.w;
            }
        } else {
#pragma unroll
            for (int j = 0; j < 64; ++j) wtmp[j] = 0.0f;
        }
        // lanes {cr, cr+16, cr+32, cr+48} hold 64 distinct elements of row c
        ss += __shfl_xor(ss, 16);
        ss += __shfl_xor(ss, 32);
        const float rn = 1.0f / fmaxf(sqrtf(ss), 1e-12f);
#pragma unroll
        for (int ks = 0; ks < 8; ++ks) {
            bf16x8 a;
#pragma unroll
            for (int j = 0; j < 8; ++j) a[j] = f2bf_rne(wtmp[ks * 8 + j] * rn);
            afrag[ct][ks] = a;
        }
    }

    // ---- stream 512 samples in 16-row tiles, B direct from global (L2-hot) ----
    float* pout = partial + (long)cg * Bn + sbase;
    for (int rt = 0; rt < SAMPLES_PER_WAVE / 16; ++rt) {
        // B layout: lane holds B[k=q*8+j][n=cr] = emb[sbase+rt*16+cr][q*8+j + 32ks]
        const short* brow = embbf + (sbase + rt * 16 + cr) * Dn + q * 8;
        bf16x8 bfrag[8];
#pragma unroll
        for (int ks = 0; ks < 8; ++ks)
            bfrag[ks] = *(const bf16x8*)(brow + ks * 32);

        f32x4 acc0 = {0.f, 0.f, 0.f, 0.f};
        f32x4 acc1 = {0.f, 0.f, 0.f, 0.f};
        f32x4 acc2 = {0.f, 0.f, 0.f, 0.f};
        f32x4 acc3 = {0.f, 0.f, 0.f, 0.f};
#pragma unroll
        for (int ks = 0; ks < 8; ++ks) {
            acc0 = __builtin_amdgcn_mfma_f32_16x16x32_bf16(afrag[0][ks], bfrag[ks], acc0, 0, 0, 0);
            acc1 = __builtin_amdgcn_mfma_f32_16x16x32_bf16(afrag[1][ks], bfrag[ks], acc1, 0, 0, 0);
            acc2 = __builtin_amdgcn_mfma_f32_16x16x32_bf16(afrag[2][ks], bfrag[ks], acc2, 0, 0, 0);
            acc3 = __builtin_amdgcn_mfma_f32_16x16x32_bf16(afrag[3][ks], bfrag[ks], acc3, 0, 0, 0);
        }

        // D layout: col=lane&15=sample, row=q*4+reg=class. Sum exp over classes.
        float s = 0.0f;
#pragma unroll
        for (int r = 0; r < 4; ++r) {
            s += __expf(SCALE_F * fminf(fmaxf(acc0[r], -1.f), 1.f));
            s += __expf(SCALE_F * fminf(fmaxf(acc1[r], -1.f), 1.f));
            s += __expf(SCALE_F * fminf(fmaxf(acc2[r], -1.f), 1.f));
            s += __expf(SCALE_F * fminf(fmaxf(acc3[r], -1.f), 1.f));
        }
        s += __shfl_xor(s, 16);
        s += __shfl_xor(s, 32);
        if (lane < 16) pout[rt * 16 + cr] = s;   // coalesced 64B store
    }
}

// ---- kernel 3: per-sample target cosine (fp32), wave-per-sample ----
__global__ __launch_bounds__(256) void k_target(const float* __restrict__ emb,
                                                const float* __restrict__ W,
                                                const int* __restrict__ tgt,
                                                float* __restrict__ numv,
                                                float* __restrict__ etv) {
    const int b    = blockIdx.x * 4 + (threadIdx.x >> 6);
    const int lane = threadIdx.x & 63;
    const int t    = tgt[b];
    float4 x = *(const float4*)(W + (long)t * Dn + lane * 4);
    float4 e = *(const float4*)(emb + b * Dn + lane * 4);
    float dot = x.x * e.x + x.y * e.y + x.z * e.z + x.w * e.w;
    float ss  = x.x * x.x + x.y * x.y + x.z * x.z + x.w * x.w;
#pragma unroll
    for (int o = 1; o < 64; o <<= 1) {
        dot += __shfl_xor(dot, o);
        ss  += __shfl_xor(ss, o);
    }
    if (lane == 0) {
        float cosv = dot / fmaxf(sqrtf(ss), 1e-12f);
        cosv = fminf(fmaxf(cosv, -1.f), 1.f);
        const float num = SCALE_F * cosf(acosf(cosv) + MARGIN_F);
        numv[b] = num;
        etv[b]  = __expf(SCALE_F * cosv);
    }
}

// ---- kernel 4: reduce partials over colgroups ----
__global__ __launch_bounds__(256) void k_rowsum(const float* __restrict__ partial,
                                                float* __restrict__ rowsum) {
    const int b = blockIdx.x * 256 + threadIdx.x;   // 8 blocks x 256
    float acc = 0.0f;
    int cg = 0;
    for (; cg + 4 <= NCG; cg += 4) {
        acc += partial[(long)(cg + 0) * Bn + b];
        acc += partial[(long)(cg + 1) * Bn + b];
        acc += partial[(long)(cg + 2) * Bn + b];
        acc += partial[(long)(cg + 3) * Bn + b];
    }
    for (; cg < NCG; ++cg) acc += partial[(long)cg * Bn + b];
    rowsum[b] = acc;
}

// ---- kernel 5: final loss reduction ----
__global__ __launch_bounds__(256) void k_loss(const float* __restrict__ numv,
                                              const float* __restrict__ etv,
                                              const float* __restrict__ rowsum,
                                              float* __restrict__ out) {
    float acc = 0.0f;
    for (int b = threadIdx.x; b < Bn; b += 256) {
        const float num  = numv[b];
        const float excl = rowsum[b] - OOB_COLS - etv[b];   // drop padding + target col
        const float denom = __expf(num) + excl;
        acc += num - logf(denom + EPS_F);
    }
#pragma unroll
    for (int o = 1; o < 64; o <<= 1) acc += __shfl_xor(acc, o);
    __shared__ float sa[4];
    const int wave = threadIdx.x >> 6, lane = threadIdx.x & 63;
    if (lane == 0) sa[wave] = acc;
    __syncthreads();
    if (threadIdx.x == 0) out[0] = -(sa[0] + sa[1] + sa[2] + sa[3]) / (float)Bn;
}

extern "C" void kernel_launch(void* const* d_in, const int* in_sizes, int n_in,
                              void* d_out, int out_size, void* d_ws, size_t ws_size,
                              hipStream_t stream) {
    const float* emb = (const float*)d_in[0];   // 2048*256
    const float* W   = (const float*)d_in[1];   // 100000*256
    const int*   tgt = (const int*)d_in[2];     // 2048
    float* out = (float*)d_out;

    char* ws = (char*)d_ws;
    short* embbf  = (short*)ws;                              // 1 MB
    float* partial = (float*)(ws + (1 << 20));               // 1563*2048*4 = 12.8 MB
    float* rowsum = partial + (long)NCG * Bn;                // 8 KB
    float* numv   = rowsum + Bn;                             // 8 KB
    float* etv    = numv + Bn;                               // 8 KB

    k_emb2bf<<<512, 256, 0, stream>>>(emb, embbf);
    k_main<<<NCG, 256, 0, stream>>>(W, embbf, partial);
    k_target<<<Bn / 4, 256, 0, stream>>>(emb, W, tgt, numv, etv);
    k_rowsum<<<Bn / 256, 256, 0, stream>>>(partial, rowsum);
    k_loss<<<1, 256, 0, stream>>>(numv, etv, rowsum, out);
}

// Round 3
// 416.891 us; speedup vs baseline: 1.2802x; 1.2802x over previous
//
#include <hip/hip_runtime.h>
#include <hip/hip_bf16.h>

// AngularMarginLoss: B=2048, D=256, C=100000
// loss = -mean_b( num_b - log(exp(num_b) + sum_{c!=t_b} exp(30*cos_bc) + 1e-6) )
// num_b = 30*cos(acos(clip(cos_bt)) + 0.2)
//
// Round-3: k_main = 782 blocks (391 col-blocks x 2 sample-halves), 4 waves.
// Wave owns 64 cols as 4x 16x16 A-tiles (normalized W, bf16, built via a
// 2-pass prologue -> no scratch spill). B staged in 32-sample double-buffered
// LDS tiles via global_load_lds(16B) with XOR chunk swizzle (coalesced write
// AND conflict-free ds_read_b128). One __syncthreads per 32 samples.

static constexpr int Bn = 2048;
static constexpr int Dn = 256;
static constexpr int Cn = 100000;
static constexpr int NCBLK  = 391;                 // col-blocks of 256 cols (100096)
static constexpr int SLICES = NCBLK * 4;           // 64-col wave slices = 1564
static constexpr float OOB_COLS = (float)(NCBLK * 256 - Cn);   // 96
static constexpr int HALF = 1024;                  // samples per block

#define SCALE_F 30.0f
#define MARGIN_F 0.2f
#define EPS_F 1e-6f

typedef __attribute__((ext_vector_type(8))) short bf16x8;   // 8 bf16 = 4 VGPRs
typedef __attribute__((ext_vector_type(4))) float f32x4;
typedef __attribute__((address_space(3))) unsigned int lds_u32;
typedef const __attribute__((address_space(1))) unsigned int g_u32;

__device__ __forceinline__ void async_cp16(const void* g, void* lds) {
    __builtin_amdgcn_global_load_lds((g_u32*)g, (lds_u32*)lds, 16, 0, 0);
}

__device__ __forceinline__ short f2bf_rne(float x) {
    union { float f; unsigned int u; } v; v.f = x;
    unsigned int r = v.u + 0x7fffu + ((v.u >> 16) & 1u);
    return (short)(r >> 16);
}

// ---- kernel 1: emb fp32 -> bf16 (row-major, 2048x256) ----
__global__ __launch_bounds__(256) void k_emb2bf(const float* __restrict__ emb,
                                                short* __restrict__ out) {
    int i = (blockIdx.x * 256 + threadIdx.x) * 4;   // 512 blocks covers 524288 exactly
    float4 x = *(const float4*)(emb + i);
    short4 o;
    o.x = f2bf_rne(x.x); o.y = f2bf_rne(x.y);
    o.z = f2bf_rne(x.z); o.w = f2bf_rne(x.w);
    *(short4*)(out + i) = o;
}

// ---- kernel 2: main fused GEMM + exp row-sum ----
__global__ __launch_bounds__(256, 2) void k_main(const float* __restrict__ W,
                                                 const short* __restrict__ embbf,
                                                 float* __restrict__ partial) {
    __shared__ __align__(16) short stage[2 * 32 * 256];   // 2 x 16KB, swizzled layout

    const int tid  = threadIdx.x;
    const int wave = tid >> 6;
    const int lane = tid & 63;
    const int q    = lane >> 4;   // quad 0..3
    const int cr   = lane & 15;

    // XCD-pair swizzle: blk and blk+8 (same XCD under %8 round-robin) are the
    // two sample-halves of one col-block -> W L2 reuse. Tail handled plainly.
    const int blk = blockIdx.x;
    int cblk, shalf;
    if (blk < 768) { cblk = ((blk >> 4) << 3) | (blk & 7); shalf = (blk >> 3) & 1; }
    else           { int t = blk - 768; cblk = 384 + (t >> 1); shalf = t & 1; }
    const int cbase = cblk * 256 + wave * 64;
    const int sbase = shalf * HALF;

    // ---- kick off staging of sample-tile 0 (overlaps with prologue) ----
    // Tile = 32 rows x 256 shorts, physical chunk p(r,c16) = r*32 + (c16 ^ (r&7)).
    // global_load_lds writes base + lane*16, so lane l of instruction i covers
    // physical chunks (wave*8 + 2i)*32 + l -> choose the GLOBAL source to match.
    {
#pragma unroll
        for (int i = 0; i < 4; ++i) {
            const int r0 = wave * 8 + 2 * i;
            const int rl = r0 + (lane >> 5);
            const int c16 = (lane & 31) ^ (rl & 7);
            const short* g = embbf + (size_t)(sbase + rl) * Dn + c16 * 8;
            async_cp16(g, (void*)(stage + r0 * 256));
        }
    }

    // ---- prologue: normalized bf16 A-fragments, 2-pass (no spill) ----
    // A layout (16x16x32): lane holds A[m=cr][k=q*8+j] per 32-wide k-step.
    bf16x8 afrag[4][8];
#pragma unroll
    for (int ct = 0; ct < 4; ++ct) {
        const int c = cbase + ct * 16 + cr;
        const float* wr = W + (size_t)c * Dn;
        float ss = 0.0f;
        if (c < Cn) {
#pragma unroll
            for (int ks = 0; ks < 8; ++ks) {
                float4 x0 = *(const float4*)(wr + ks * 32 + q * 8);
                float4 x1 = *(const float4*)(wr + ks * 32 + q * 8 + 4);
                ss += x0.x * x0.x + x0.y * x0.y + x0.z * x0.z + x0.w * x0.w;
                ss += x1.x * x1.x + x1.y * x1.y + x1.z * x1.z + x1.w * x1.w;
            }
        }
        ss += __shfl_xor(ss, 16);
        ss += __shfl_xor(ss, 32);
        const float rn = 1.0f / fmaxf(sqrtf(ss), 1e-12f);
#pragma unroll
        for (int ks = 0; ks < 8; ++ks) {
            bf16x8 a = {0, 0, 0, 0, 0, 0, 0, 0};
            if (c < Cn) {     // pass 2: reload (L2-hot), scale, convert in place
                float4 x0 = *(const float4*)(wr + ks * 32 + q * 8);
                float4 x1 = *(const float4*)(wr + ks * 32 + q * 8 + 4);
                a[0] = f2bf_rne(x0.x * rn); a[1] = f2bf_rne(x0.y * rn);
                a[2] = f2bf_rne(x0.z * rn); a[3] = f2bf_rne(x0.w * rn);
                a[4] = f2bf_rne(x1.x * rn); a[5] = f2bf_rne(x1.y * rn);
                a[6] = f2bf_rne(x1.z * rn); a[7] = f2bf_rne(x1.w * rn);
            }
            afrag[ct][ks] = a;
        }
    }

    __syncthreads();   // staging of tile 0 complete (drains vmcnt)

    float* pout = partial + (size_t)(cblk * 4 + wave) * Bn + sbase;
    const int sw = cr & 7;

    for (int it = 0; it < HALF / 32; ++it) {
        const int buf = it & 1;
        // async-stage next tile into the other buffer
        if (it + 1 < HALF / 32) {
#pragma unroll
            for (int i = 0; i < 4; ++i) {
                const int r0 = wave * 8 + 2 * i;
                const int rl = r0 + (lane >> 5);
                const int c16 = (lane & 31) ^ (rl & 7);
                const short* g = embbf + (size_t)(sbase + (it + 1) * 32 + rl) * Dn + c16 * 8;
                async_cp16(g, (void*)(stage + (buf ^ 1) * (32 * 256) + r0 * 256));
            }
        }

        const short* sb = stage + buf * (32 * 256);
#pragma unroll
        for (int st = 0; st < 2; ++st) {
            // B layout: lane holds B[k=q*8+j][n=cr] = emb[row][k]; row = st*16+cr.
            // Chunk (4ks+q) of row, de-swizzled: phys = (4ks+q) ^ (cr&7).
            const short* rowp = sb + (st * 16 + cr) * 256;
            bf16x8 bfrag[8];
#pragma unroll
            for (int ks = 0; ks < 8; ++ks)
                bfrag[ks] = *(const bf16x8*)(rowp + ((((ks << 2) | q) ^ sw) << 3));

            f32x4 acc0 = {0.f, 0.f, 0.f, 0.f};
            f32x4 acc1 = {0.f, 0.f, 0.f, 0.f};
            f32x4 acc2 = {0.f, 0.f, 0.f, 0.f};
            f32x4 acc3 = {0.f, 0.f, 0.f, 0.f};
#pragma unroll
            for (int ks = 0; ks < 8; ++ks) {
                acc0 = __builtin_amdgcn_mfma_f32_16x16x32_bf16(afrag[0][ks], bfrag[ks], acc0, 0, 0, 0);
                acc1 = __builtin_amdgcn_mfma_f32_16x16x32_bf16(afrag[1][ks], bfrag[ks], acc1, 0, 0, 0);
                acc2 = __builtin_amdgcn_mfma_f32_16x16x32_bf16(afrag[2][ks], bfrag[ks], acc2, 0, 0, 0);
                acc3 = __builtin_amdgcn_mfma_f32_16x16x32_bf16(afrag[3][ks], bfrag[ks], acc3, 0, 0, 0);
            }

            // D layout: col=lane&15=sample, row=q*4+reg=class. Sum exp over classes.
            float s = 0.0f;
#pragma unroll
            for (int r = 0; r < 4; ++r) {
                s += __expf(SCALE_F * fminf(fmaxf(acc0[r], -1.f), 1.f));
                s += __expf(SCALE_F * fminf(fmaxf(acc1[r], -1.f), 1.f));
                s += __expf(SCALE_F * fminf(fmaxf(acc2[r], -1.f), 1.f));
                s += __expf(SCALE_F * fminf(fmaxf(acc3[r], -1.f), 1.f));
            }
            s += __shfl_xor(s, 16);
            s += __shfl_xor(s, 32);
            if (lane < 16) pout[it * 32 + st * 16 + cr] = s;   // coalesced 64B
        }
        __syncthreads();   // drains async stage of tile it+1, fences buf reuse
    }
}

// ---- kernel 3: per-sample target cosine (fp32), wave-per-sample ----
__global__ __launch_bounds__(256) void k_target(const float* __restrict__ emb,
                                                const float* __restrict__ W,
                                                const int* __restrict__ tgt,
                                                float* __restrict__ numv,
                                                float* __restrict__ etv) {
    const int b    = blockIdx.x * 4 + (threadIdx.x >> 6);
    const int lane = threadIdx.x & 63;
    const int t    = tgt[b];
    float4 x = *(const float4*)(W + (size_t)t * Dn + lane * 4);
    float4 e = *(const float4*)(emb + b * Dn + lane * 4);
    float dot = x.x * e.x + x.y * e.y + x.z * e.z + x.w * e.w;
    float ss  = x.x * x.x + x.y * x.y + x.z * x.z + x.w * x.w;
#pragma unroll
    for (int o = 1; o < 64; o <<= 1) {
        dot += __shfl_xor(dot, o);
        ss  += __shfl_xor(ss, o);
    }
    if (lane == 0) {
        float cosv = dot / fmaxf(sqrtf(ss), 1e-12f);
        cosv = fminf(fmaxf(cosv, -1.f), 1.f);
        const float num = SCALE_F * cosf(acosf(cosv) + MARGIN_F);
        numv[b] = num;
        etv[b]  = __expf(SCALE_F * cosv);
    }
}

// ---- kernel 4: reduce partials over slices ----
__global__ __launch_bounds__(256) void k_rowsum(const float* __restrict__ partial,
                                                float* __restrict__ rowsum) {
    const int b = blockIdx.x * 256 + threadIdx.x;   // 8 blocks x 256
    float acc = 0.0f;
    int s = 0;
    for (; s + 4 <= SLICES; s += 4) {
        acc += partial[(size_t)(s + 0) * Bn + b];
        acc += partial[(size_t)(s + 1) * Bn + b];
        acc += partial[(size_t)(s + 2) * Bn + b];
        acc += partial[(size_t)(s + 3) * Bn + b];
    }
    for (; s < SLICES; ++s) acc += partial[(size_t)s * Bn + b];
    rowsum[b] = acc;
}

// ---- kernel 5: final loss reduction ----
__global__ __launch_bounds__(256) void k_loss(const float* __restrict__ numv,
                                              const float* __restrict__ etv,
                                              const float* __restrict__ rowsum,
                                              float* __restrict__ out) {
    float acc = 0.0f;
    for (int b = threadIdx.x; b < Bn; b += 256) {
        const float num  = numv[b];
        const float excl = rowsum[b] - OOB_COLS - etv[b];   // drop padding + target col
        const float denom = __expf(num) + excl;
        acc += num - logf(denom + EPS_F);
    }
#pragma unroll
    for (int o = 1; o < 64; o <<= 1) acc += __shfl_xor(acc, o);
    __shared__ float sa[4];
    const int wave = threadIdx.x >> 6, lane = threadIdx.x & 63;
    if (lane == 0) sa[wave] = acc;
    __syncthreads();
    if (threadIdx.x == 0) out[0] = -(sa[0] + sa[1] + sa[2] + sa[3]) / (float)Bn;
}

extern "C" void kernel_launch(void* const* d_in, const int* in_sizes, int n_in,
                              void* d_out, int out_size, void* d_ws, size_t ws_size,
                              hipStream_t stream) {
    const float* emb = (const float*)d_in[0];   // 2048*256
    const float* W   = (const float*)d_in[1];   // 100000*256
    const int*   tgt = (const int*)d_in[2];     // 2048
    float* out = (float*)d_out;

    char* ws = (char*)d_ws;
    short* embbf   = (short*)ws;                             // 1 MB
    float* partial = (float*)(ws + (1 << 20));               // 1564*2048*4 = 12.8 MB
    float* rowsum  = partial + (size_t)SLICES * Bn;          // 8 KB
    float* numv    = rowsum + Bn;                            // 8 KB
    float* etv     = numv + Bn;                              // 8 KB

    k_emb2bf<<<512, 256, 0, stream>>>(emb, embbf);
    k_main<<<NCBLK * 2, 256, 0, stream>>>(W, embbf, partial);
    k_target<<<Bn / 4, 256, 0, stream>>>(emb, W, tgt, numv, etv);
    k_rowsum<<<Bn / 256, 256, 0, stream>>>(partial, rowsum);
    k_loss<<<1, 256, 0, stream>>>(numv, etv, rowsum, out);
}